// Round 3
// baseline (1624.073 us; speedup 1.0000x reference)
//
#include <hip/hip_runtime.h>
#include <cstdint>
#include <cstddef>

#define GRID_DIM 160
#define GRID_VOX (GRID_DIM * GRID_DIM * GRID_DIM)
#define CIN 64
#define COUT 96
#define NK 27
#define CAP_SIDE 65536          // capacity per side-offset pair list (measured ~16k)
#define PAIRS_PER_BLOCK 64

// ---------------------------------------------------------------------------
// K1: scatter point indices into dense voxel grid. Grid pre-memset to -1.
// atomicMax = last-update-wins (matches numpy scatter order), verified R1.
// ---------------------------------------------------------------------------
__global__ __launch_bounds__(256) void scatter_kernel(
    const int* __restrict__ coords, int* __restrict__ grid, int N)
{
    int i = blockIdx.x * 256 + threadIdx.x;
    if (i >= N) return;
    int lin = (coords[i * 3] * GRID_DIM + coords[i * 3 + 1]) * GRID_DIM
            + coords[i * 3 + 2];
    atomicMax(&grid[lin], i);
}

// ---------------------------------------------------------------------------
// K2: repack weight [27][64][96] -> [27][16][96][4] (wt2[k][ci4][c][j]).
// ---------------------------------------------------------------------------
__global__ __launch_bounds__(256) void repack_w(
    const float* __restrict__ w, float* __restrict__ wt2)
{
    int idx = blockIdx.x * 256 + threadIdx.x;
    if (idx >= NK * CIN * COUT) return;
    int k   = idx / (CIN * COUT);
    int r   = idx - k * (CIN * COUT);
    int ci  = r / COUT;
    int c   = r - ci * COUT;
    wt2[(((size_t)k * 16 + (ci >> 2)) * COUT + c) * 4 + (ci & 3)] = w[idx];
}

// ---------------------------------------------------------------------------
// K3: build rulebook — for each point, probe the 26 non-center offsets and
// append (src,dst) into per-offset segments. Center (k=13) handled in K5.
// ---------------------------------------------------------------------------
__global__ __launch_bounds__(256) void fill_pairs(
    const int* __restrict__ coords, const int* __restrict__ grid,
    int* __restrict__ cursors, int2* __restrict__ pairs, int N)
{
    int p = blockIdx.x * 256 + threadIdx.x;
    if (p >= N) return;
    int c0 = coords[p * 3], c1 = coords[p * 3 + 1], c2 = coords[p * 3 + 2];

    #pragma unroll
    for (int k = 0; k < NK; ++k) {
        if (k == 13) continue;                      // center: handled in LN pass
        int dz = k / 9 - 1, dy = (k / 3) % 3 - 1, dx = k % 3 - 1;
        int a0 = c0 + dz, a1 = c1 + dy, a2 = c2 + dx;
        if ((unsigned)a0 >= GRID_DIM || (unsigned)a1 >= GRID_DIM ||
            (unsigned)a2 >= GRID_DIM) continue;
        int nidx = grid[(a0 * GRID_DIM + a1) * GRID_DIM + a2];
        if (nidx < 0) continue;
        int si = (k < 13) ? k : k - 1;              // side index 0..25
        int slot = atomicAdd(&cursors[si], 1);
        if (slot < CAP_SIDE)
            pairs[(size_t)si * CAP_SIDE + slot] = make_int2(nidx, p);
    }
}

// ---------------------------------------------------------------------------
// K4: side-offset gather-GEMM-scatter. One block = one offset b, 64 pairs.
// W[b] staged in LDS once per block; half-wave per pair; atomicAdd scatter.
// ---------------------------------------------------------------------------
__global__ __launch_bounds__(256) void conv_side(
    const float* __restrict__ feat, const float* __restrict__ wt2,
    const int* __restrict__ cursors, const int2* __restrict__ pairs,
    float* __restrict__ out)
{
    int si = blockIdx.y;                    // 0..25
    int k  = (si < 13) ? si : si + 1;
    int cnt = cursors[si];
    if (cnt > CAP_SIDE) cnt = CAP_SIDE;
    int base = blockIdx.x * PAIRS_PER_BLOCK;
    if (base >= cnt) return;                // uniform early-exit (before barrier)

    __shared__ float4 wlds[16 * COUT];      // 24576 B: wlds[ci4*96 + c]
    {
        const float4* src = (const float4*)(wt2 + (size_t)k * 16 * COUT * 4);
        for (int i = threadIdx.x; i < 16 * COUT; i += 256) wlds[i] = src[i];
    }
    __syncthreads();

    int hw = threadIdx.x >> 5;              // half-wave id 0..7
    int h  = threadIdx.x & 31;
    const int2* seg = pairs + (size_t)si * CAP_SIDE;

    for (int j = hw; j < PAIRS_PER_BLOCK; j += 8) {
        int idx = base + j;
        if (idx >= cnt) break;              // idx monotone in j
        int2 pr = seg[idx];
        const float4* fp = (const float4*)(feat + (size_t)pr.x * CIN);

        float a0 = 0.f, a1 = 0.f, a2 = 0.f;
        #pragma unroll
        for (int ci4 = 0; ci4 < 16; ++ci4) {
            float4 f  = fp[ci4];
            const float4* w = &wlds[ci4 * COUT];
            float4 wa = w[h], wb = w[h + 32], wc = w[h + 64];
            a0 = fmaf(f.w, wa.w, fmaf(f.z, wa.z, fmaf(f.y, wa.y, fmaf(f.x, wa.x, a0))));
            a1 = fmaf(f.w, wb.w, fmaf(f.z, wb.z, fmaf(f.y, wb.y, fmaf(f.x, wb.x, a1))));
            a2 = fmaf(f.w, wc.w, fmaf(f.z, wc.z, fmaf(f.y, wc.y, fmaf(f.x, wc.x, a2))));
        }
        float* op = out + (size_t)pr.y * COUT;
        atomicAdd(op + h,      a0);
        atomicAdd(op + h + 32, a1);
        atomicAdd(op + h + 64, a2);
    }
}

// ---------------------------------------------------------------------------
// K5: center contribution (LDS-staged W[13], coalesced feat reads) + bias +
// LayerNorm + ReLU, in place on `out` (which holds the side-offset sums).
// Center src = grid[coords[p]] (scatter winner), NOT p — duplicate-coord safe.
// ---------------------------------------------------------------------------
__global__ __launch_bounds__(256) void center_ln_relu(
    const float* __restrict__ feat, const int* __restrict__ coords,
    const int* __restrict__ grid, const float* __restrict__ wt2,
    const float* __restrict__ bias, const float* __restrict__ gamma,
    const float* __restrict__ beta, float* __restrict__ out, int N)
{
    __shared__ float4 wlds[16 * COUT];
    {
        const float4* src = (const float4*)(wt2 + (size_t)13 * 16 * COUT * 4);
        for (int i = threadIdx.x; i < 16 * COUT; i += 256) wlds[i] = src[i];
    }
    __syncthreads();

    int hw = threadIdx.x >> 5;
    int h  = threadIdx.x & 31;
    float b0 = bias[h], b1 = bias[h + 32], b2 = bias[h + 64];
    float g0 = gamma[h], g1 = gamma[h + 32], g2 = gamma[h + 64];
    float e0 = beta[h],  e1 = beta[h + 32],  e2 = beta[h + 64];

    int pbase = blockIdx.x * 128;
    for (int i = 0; i < 16; ++i) {
        int p = pbase + i * 8 + hw;
        if (p >= N) continue;               // uniform within the half-wave

        int lin = (coords[p * 3] * GRID_DIM + coords[p * 3 + 1]) * GRID_DIM
                + coords[p * 3 + 2];
        int src = grid[lin];                // >= 0 (p itself was scattered)
        const float4* fp = (const float4*)(feat + (size_t)src * CIN);

        float* op = out + (size_t)p * COUT;
        float a0 = op[h]      + b0;
        float a1 = op[h + 32] + b1;
        float a2 = op[h + 64] + b2;

        #pragma unroll
        for (int ci4 = 0; ci4 < 16; ++ci4) {
            float4 f  = fp[ci4];
            const float4* w = &wlds[ci4 * COUT];
            float4 wa = w[h], wb = w[h + 32], wc = w[h + 64];
            a0 = fmaf(f.w, wa.w, fmaf(f.z, wa.z, fmaf(f.y, wa.y, fmaf(f.x, wa.x, a0))));
            a1 = fmaf(f.w, wb.w, fmaf(f.z, wb.z, fmaf(f.y, wb.y, fmaf(f.x, wb.x, a1))));
            a2 = fmaf(f.w, wc.w, fmaf(f.z, wc.z, fmaf(f.y, wc.y, fmaf(f.x, wc.x, a2))));
        }

        float s  = a0 + a1 + a2;
        float s2 = a0 * a0 + a1 * a1 + a2 * a2;
        #pragma unroll
        for (int off = 16; off >= 1; off >>= 1) {
            s  += __shfl_xor(s, off);       // stays within the 32-lane half
            s2 += __shfl_xor(s2, off);
        }
        float mu  = s * (1.0f / COUT);
        float var = s2 * (1.0f / COUT) - mu * mu;
        float rs  = rsqrtf(var + 1e-5f);

        float o0 = (a0 - mu) * rs * g0 + e0;
        float o1 = (a1 - mu) * rs * g1 + e1;
        float o2 = (a2 - mu) * rs * g2 + e2;
        op[h]      = o0 > 0.f ? o0 : 0.f;
        op[h + 32] = o1 > 0.f ? o1 : 0.f;
        op[h + 64] = o2 > 0.f ? o2 : 0.f;
    }
}

// ---------------------------------------------------------------------------
extern "C" void kernel_launch(void* const* d_in, const int* in_sizes, int n_in,
                              void* d_out, int out_size, void* d_ws, size_t ws_size,
                              hipStream_t stream)
{
    const float* feat   = (const float*)d_in[0];
    const int*   coords = (const int*)d_in[1];
    const float* weight = (const float*)d_in[2];
    const float* bias   = (const float*)d_in[3];
    const float* gamma  = (const float*)d_in[4];
    const float* beta   = (const float*)d_in[5];
    float* out = (float*)d_out;

    int N = in_sizes[0] / CIN;   // 262144

    // Workspace layout (all 16B-aligned):
    //   [0, 16384000)      voxel grid (int32)
    //   [+663552)          repacked weight
    //   [+256)             26 pair-list cursors
    //   [+26*65536*8)      pair lists (int2), per-side segments
    char* wsp = (char*)d_ws;
    int*   grid_ws = (int*)wsp;                       wsp += (size_t)GRID_VOX * 4;
    float* wt2     = (float*)wsp;                     wsp += (size_t)NK * CIN * COUT * 4;
    int*   cursors = (int*)wsp;                       wsp += 256;
    int2*  pairs   = (int2*)wsp;

    hipMemsetAsync(grid_ws, 0xFF, (size_t)GRID_VOX * 4, stream);
    hipMemsetAsync(cursors, 0, 256, stream);
    hipMemsetAsync(out, 0, (size_t)N * COUT * 4, stream);

    scatter_kernel<<<(N + 255) / 256, 256, 0, stream>>>(coords, grid_ws, N);
    repack_w<<<(NK * CIN * COUT + 255) / 256, 256, 0, stream>>>(weight, wt2);
    fill_pairs<<<(N + 255) / 256, 256, 0, stream>>>(coords, grid_ws, cursors,
                                                    pairs, N);

    dim3 gside(CAP_SIDE / PAIRS_PER_BLOCK, 26);       // 1024 x 26, early-exit tail
    conv_side<<<gside, 256, 0, stream>>>(feat, wt2, cursors, pairs, out);

    center_ln_relu<<<(N + 127) / 128, 256, 0, stream>>>(
        feat, coords, grid_ws, wt2, bias, gamma, beta, out, N);
}

// Round 4
// 1412.026 us; speedup vs baseline: 1.1502x; 1.1502x over previous
//
#include <hip/hip_runtime.h>
#include <cstdint>
#include <cstddef>

#define GRID_DIM 160
#define GRID_VOX (GRID_DIM * GRID_DIM * GRID_DIM)
#define CIN 64
#define COUT 96
#define NK 27
#define NSIDE 26
#define CAP_SIDE 65536          // capacity per side-offset pair list (measured ~16k)
#define PAIRS_PER_BLOCK 64

// ---------------------------------------------------------------------------
// K1: scatter point indices into dense voxel grid. Grid pre-memset to -1.
// atomicMax = last-update-wins (matches numpy scatter order), verified R1.
// ---------------------------------------------------------------------------
__global__ __launch_bounds__(256) void scatter_kernel(
    const int* __restrict__ coords, int* __restrict__ grid, int N)
{
    int i = blockIdx.x * 256 + threadIdx.x;
    if (i >= N) return;
    int lin = (coords[i * 3] * GRID_DIM + coords[i * 3 + 1]) * GRID_DIM
            + coords[i * 3 + 2];
    atomicMax(&grid[lin], i);
}

// ---------------------------------------------------------------------------
// K2: repack weight [27][64][96] -> [27][16][96][4] (wt2[k][ci4][c][j]).
// ---------------------------------------------------------------------------
__global__ __launch_bounds__(256) void repack_w(
    const float* __restrict__ w, float* __restrict__ wt2)
{
    int idx = blockIdx.x * 256 + threadIdx.x;
    if (idx >= NK * CIN * COUT) return;
    int k   = idx / (CIN * COUT);
    int r   = idx - k * (CIN * COUT);
    int ci  = r / COUT;
    int c   = r - ci * COUT;
    wt2[(((size_t)k * 16 + (ci >> 2)) * COUT + c) * 4 + (ci & 3)] = w[idx];
}

// ---------------------------------------------------------------------------
// K3: build rulebook, wave-aggregated.
// Phase 1: all 26 probes issued up-front (fully unrolled -> 26 loads in
// flight, one latency exposure instead of 26 serial ones).
// Phase 2: per offset, ballot valid lanes; ONE atomicAdd per wave (leader),
// lanes place entries at base + popc-prefix. 6.8M atomics -> 106k.
// ---------------------------------------------------------------------------
__global__ __launch_bounds__(256) void fill_pairs(
    const int* __restrict__ coords, const int* __restrict__ grid,
    int* __restrict__ cursors, int2* __restrict__ pairs, int N)
{
    int p = blockIdx.x * 256 + threadIdx.x;
    if (p >= N) return;
    int lane = threadIdx.x & 63;

    int c0 = coords[p * 3], c1 = coords[p * 3 + 1], c2 = coords[p * 3 + 2];

    int nidx[NSIDE];
    #pragma unroll
    for (int si = 0; si < NSIDE; ++si) {
        int k = (si < 13) ? si : si + 1;
        int dz = k / 9 - 1, dy = (k / 3) % 3 - 1, dx = k % 3 - 1;
        int a0 = c0 + dz, a1 = c1 + dy, a2 = c2 + dx;
        nidx[si] = -1;
        if ((unsigned)a0 < GRID_DIM && (unsigned)a1 < GRID_DIM &&
            (unsigned)a2 < GRID_DIM) {
            nidx[si] = grid[(a0 * GRID_DIM + a1) * GRID_DIM + a2];
        }
    }

    #pragma unroll
    for (int si = 0; si < NSIDE; ++si) {
        bool valid = nidx[si] >= 0;
        unsigned long long mask = __ballot(valid);
        if (mask == 0ull) continue;               // wave-uniform skip
        int leader = __ffsll((long long)mask) - 1;
        int cnt    = __popcll(mask);
        int myoff  = __popcll(mask & ((1ull << lane) - 1ull));
        int base   = 0;
        if (lane == leader) base = atomicAdd(&cursors[si], cnt);
        base = __shfl(base, leader);
        int slot = base + myoff;
        if (valid && slot < CAP_SIDE)
            pairs[(size_t)si * CAP_SIDE + slot] = make_int2(nidx[si], p);
    }
}

// ---------------------------------------------------------------------------
// K4: side-offset gather-GEMM-scatter. One block = one offset b, 64 pairs.
// W[b] staged in LDS once per block; half-wave per pair; atomicAdd scatter.
// ---------------------------------------------------------------------------
__global__ __launch_bounds__(256) void conv_side(
    const float* __restrict__ feat, const float* __restrict__ wt2,
    const int* __restrict__ cursors, const int2* __restrict__ pairs,
    float* __restrict__ out)
{
    int si = blockIdx.y;                    // 0..25
    int k  = (si < 13) ? si : si + 1;
    int cnt = cursors[si];
    if (cnt > CAP_SIDE) cnt = CAP_SIDE;
    int base = blockIdx.x * PAIRS_PER_BLOCK;
    if (base >= cnt) return;                // uniform early-exit (before barrier)

    __shared__ float4 wlds[16 * COUT];      // 24576 B: wlds[ci4*96 + c]
    {
        const float4* src = (const float4*)(wt2 + (size_t)k * 16 * COUT * 4);
        for (int i = threadIdx.x; i < 16 * COUT; i += 256) wlds[i] = src[i];
    }
    __syncthreads();

    int hw = threadIdx.x >> 5;              // half-wave id 0..7
    int h  = threadIdx.x & 31;
    const int2* seg = pairs + (size_t)si * CAP_SIDE;

    for (int j = hw; j < PAIRS_PER_BLOCK; j += 8) {
        int idx = base + j;
        if (idx >= cnt) break;              // idx monotone in j
        int2 pr = seg[idx];
        const float4* fp = (const float4*)(feat + (size_t)pr.x * CIN);

        float a0 = 0.f, a1 = 0.f, a2 = 0.f;
        #pragma unroll
        for (int ci4 = 0; ci4 < 16; ++ci4) {
            float4 f  = fp[ci4];
            const float4* w = &wlds[ci4 * COUT];
            float4 wa = w[h], wb = w[h + 32], wc = w[h + 64];
            a0 = fmaf(f.w, wa.w, fmaf(f.z, wa.z, fmaf(f.y, wa.y, fmaf(f.x, wa.x, a0))));
            a1 = fmaf(f.w, wb.w, fmaf(f.z, wb.z, fmaf(f.y, wb.y, fmaf(f.x, wb.x, a1))));
            a2 = fmaf(f.w, wc.w, fmaf(f.z, wc.z, fmaf(f.y, wc.y, fmaf(f.x, wc.x, a2))));
        }
        float* op = out + (size_t)pr.y * COUT;
        atomicAdd(op + h,      a0);
        atomicAdd(op + h + 32, a1);
        atomicAdd(op + h + 64, a2);
    }
}

// ---------------------------------------------------------------------------
// K5: center contribution (LDS-staged W[13], coalesced feat reads) + bias +
// LayerNorm + ReLU, in place on `out` (which holds the side-offset sums).
// Center src = grid[coords[p]] (scatter winner), NOT p — duplicate-coord safe.
// ---------------------------------------------------------------------------
__global__ __launch_bounds__(256) void center_ln_relu(
    const float* __restrict__ feat, const int* __restrict__ coords,
    const int* __restrict__ grid, const float* __restrict__ wt2,
    const float* __restrict__ bias, const float* __restrict__ gamma,
    const float* __restrict__ beta, float* __restrict__ out, int N)
{
    __shared__ float4 wlds[16 * COUT];
    {
        const float4* src = (const float4*)(wt2 + (size_t)13 * 16 * COUT * 4);
        for (int i = threadIdx.x; i < 16 * COUT; i += 256) wlds[i] = src[i];
    }
    __syncthreads();

    int hw = threadIdx.x >> 5;
    int h  = threadIdx.x & 31;
    float b0 = bias[h], b1 = bias[h + 32], b2 = bias[h + 64];
    float g0 = gamma[h], g1 = gamma[h + 32], g2 = gamma[h + 64];
    float e0 = beta[h],  e1 = beta[h + 32],  e2 = beta[h + 64];

    int pbase = blockIdx.x * 128;
    for (int i = 0; i < 16; ++i) {
        int p = pbase + i * 8 + hw;
        if (p >= N) continue;               // uniform within the half-wave

        int lin = (coords[p * 3] * GRID_DIM + coords[p * 3 + 1]) * GRID_DIM
                + coords[p * 3 + 2];
        int src = grid[lin];                // >= 0 (p itself was scattered)
        const float4* fp = (const float4*)(feat + (size_t)src * CIN);

        float* op = out + (size_t)p * COUT;
        float a0 = op[h]      + b0;
        float a1 = op[h + 32] + b1;
        float a2 = op[h + 64] + b2;

        #pragma unroll
        for (int ci4 = 0; ci4 < 16; ++ci4) {
            float4 f  = fp[ci4];
            const float4* w = &wlds[ci4 * COUT];
            float4 wa = w[h], wb = w[h + 32], wc = w[h + 64];
            a0 = fmaf(f.w, wa.w, fmaf(f.z, wa.z, fmaf(f.y, wa.y, fmaf(f.x, wa.x, a0))));
            a1 = fmaf(f.w, wb.w, fmaf(f.z, wb.z, fmaf(f.y, wb.y, fmaf(f.x, wb.x, a1))));
            a2 = fmaf(f.w, wc.w, fmaf(f.z, wc.z, fmaf(f.y, wc.y, fmaf(f.x, wc.x, a2))));
        }

        float s  = a0 + a1 + a2;
        float s2 = a0 * a0 + a1 * a1 + a2 * a2;
        #pragma unroll
        for (int off = 16; off >= 1; off >>= 1) {
            s  += __shfl_xor(s, off);       // stays within the 32-lane half
            s2 += __shfl_xor(s2, off);
        }
        float mu  = s * (1.0f / COUT);
        float var = s2 * (1.0f / COUT) - mu * mu;
        float rs  = rsqrtf(var + 1e-5f);

        float o0 = (a0 - mu) * rs * g0 + e0;
        float o1 = (a1 - mu) * rs * g1 + e1;
        float o2 = (a2 - mu) * rs * g2 + e2;
        op[h]      = o0 > 0.f ? o0 : 0.f;
        op[h + 32] = o1 > 0.f ? o1 : 0.f;
        op[h + 64] = o2 > 0.f ? o2 : 0.f;
    }
}

// ---------------------------------------------------------------------------
extern "C" void kernel_launch(void* const* d_in, const int* in_sizes, int n_in,
                              void* d_out, int out_size, void* d_ws, size_t ws_size,
                              hipStream_t stream)
{
    const float* feat   = (const float*)d_in[0];
    const int*   coords = (const int*)d_in[1];
    const float* weight = (const float*)d_in[2];
    const float* bias   = (const float*)d_in[3];
    const float* gamma  = (const float*)d_in[4];
    const float* beta   = (const float*)d_in[5];
    float* out = (float*)d_out;

    int N = in_sizes[0] / CIN;   // 262144

    // Workspace layout (all 16B-aligned):
    //   [0, 16384000)      voxel grid (int32)
    //   [+663552)          repacked weight
    //   [+256)             26 pair-list cursors
    //   [+26*65536*8)      pair lists (int2), per-side segments
    char* wsp = (char*)d_ws;
    int*   grid_ws = (int*)wsp;                       wsp += (size_t)GRID_VOX * 4;
    float* wt2     = (float*)wsp;                     wsp += (size_t)NK * CIN * COUT * 4;
    int*   cursors = (int*)wsp;                       wsp += 256;
    int2*  pairs   = (int2*)wsp;

    hipMemsetAsync(grid_ws, 0xFF, (size_t)GRID_VOX * 4, stream);
    hipMemsetAsync(cursors, 0, 256, stream);
    hipMemsetAsync(out, 0, (size_t)N * COUT * 4, stream);

    scatter_kernel<<<(N + 255) / 256, 256, 0, stream>>>(coords, grid_ws, N);
    repack_w<<<(NK * CIN * COUT + 255) / 256, 256, 0, stream>>>(weight, wt2);
    fill_pairs<<<(N + 255) / 256, 256, 0, stream>>>(coords, grid_ws, cursors,
                                                    pairs, N);

    dim3 gside(CAP_SIDE / PAIRS_PER_BLOCK, 26);       // 1024 x 26, early-exit tail
    conv_side<<<gside, 256, 0, stream>>>(feat, wt2, cursors, pairs, out);

    center_ln_relu<<<(N + 127) / 128, 256, 0, stream>>>(
        feat, coords, grid_ws, wt2, bias, gamma, beta, out, N);
}

// Round 5
// 640.223 us; speedup vs baseline: 2.5367x; 2.2055x over previous
//
#include <hip/hip_runtime.h>
#include <cstdint>
#include <cstddef>

#define GRID_DIM 160
#define GRID_VOX (GRID_DIM * GRID_DIM * GRID_DIM)
#define CIN 64
#define COUT 96
#define NK 27
#define NSIDE 26
#define CAP_SIDE 65536          // capacity per side-offset pair list (measured ~16k)
#define PAIRS_PER_BLOCK 64
#define CURS_STRIDE 16          // cursors 64B apart -> no same-line atomic contention

// ---------------------------------------------------------------------------
// K1: scatter point indices into dense voxel grid. Grid pre-memset to -1.
// atomicMax = last-update-wins (matches numpy scatter order), verified R1.
// ---------------------------------------------------------------------------
__global__ __launch_bounds__(256) void scatter_kernel(
    const int* __restrict__ coords, int* __restrict__ grid, int N)
{
    int i = blockIdx.x * 256 + threadIdx.x;
    if (i >= N) return;
    int lin = (coords[i * 3] * GRID_DIM + coords[i * 3 + 1]) * GRID_DIM
            + coords[i * 3 + 2];
    atomicMax(&grid[lin], i);
}

// ---------------------------------------------------------------------------
// K2: repack weight [27][64][96] -> [27][16][96][4] (wt2[k][ci4][c][j]).
// ---------------------------------------------------------------------------
__global__ __launch_bounds__(256) void repack_w(
    const float* __restrict__ w, float* __restrict__ wt2)
{
    int idx = blockIdx.x * 256 + threadIdx.x;
    if (idx >= NK * CIN * COUT) return;
    int k   = idx / (CIN * COUT);
    int r   = idx - k * (CIN * COUT);
    int ci  = r / COUT;
    int c   = r - ci * COUT;
    wt2[(((size_t)k * 16 + (ci >> 2)) * COUT + c) * 4 + (ci & 3)] = w[idx];
}

// ---------------------------------------------------------------------------
// K3: build rulebook with mirror symmetry + forced probe MLP.
// Phase 1: 13 side probes (k=0..12) + center, ALL issued branchlessly before
// any consumer (asm-pinned) -> one vmcnt wait instead of 26 serial chains.
// Phase 2: per k, wave-aggregated append of:
//   own    entry (src=nidx[k], dst=p, list k)           -- every point
//   mirror entry (src=w,       dst=nidx[k], list 25-k)  -- cell winners only
// Mirror completeness: every winner receives all 26 side contributions
// (own probes cover k<13, neighbor mirrors cover k>13, one per occupied
// neighbor cell). Losers (duplicate coords, ~8k) are fixed by dup_fix.
// ---------------------------------------------------------------------------
__global__ __launch_bounds__(256, 4) void fill_pairs(
    const int* __restrict__ coords, const int* __restrict__ grid,
    int* __restrict__ cursors, int2* __restrict__ pairs,
    int* __restrict__ winner, int N)
{
    int p = blockIdx.x * 256 + threadIdx.x;
    if (p >= N) return;
    int lane = threadIdx.x & 63;

    int c0 = coords[p * 3], c1 = coords[p * 3 + 1], c2 = coords[p * 3 + 2];
    int ownLin = (c0 * GRID_DIM + c1) * GRID_DIM + c2;

    // ---- phase 1: issue all probes with max MLP (branchless, clamped) ----
    int nidx[13];
    #pragma unroll
    for (int k = 0; k < 13; ++k) {
        int dz = k / 9 - 1, dy = (k / 3) % 3 - 1, dx = k % 3 - 1;
        int a0 = c0 + dz, a1 = c1 + dy, a2 = c2 + dx;
        bool v = ((unsigned)a0 < GRID_DIM) & ((unsigned)a1 < GRID_DIM) &
                 ((unsigned)a2 < GRID_DIM);
        int lin = v ? (a0 * GRID_DIM + a1) * GRID_DIM + a2 : ownLin;
        int g = grid[lin];              // always issued (safe addr)
        nidx[k] = v ? g : -1;
    }
    int w = grid[ownLin];               // center probe (>=0: p was scattered)

    // pin: force all 14 loads in flight / completed here, not interleaved
    int chk = w;
    #pragma unroll
    for (int k = 0; k < 13; ++k) chk += nidx[k];
    asm volatile("" :: "v"(chk));

    winner[p] = w;
    bool isW = (w == p);

    // ---- phase 2: wave-aggregated appends ----
    #pragma unroll
    for (int k = 0; k < 13; ++k) {
        int q = nidx[k];
        bool valid = q >= 0;

        // own entry -> list k
        unsigned long long m1 = __ballot(valid);
        if (m1) {
            int leader = __ffsll((long long)m1) - 1;
            int cnt    = __popcll(m1);
            int off    = __popcll(m1 & ((1ull << lane) - 1ull));
            int base = 0;
            if (lane == leader) base = atomicAdd(&cursors[k * CURS_STRIDE], cnt);
            base = __shfl(base, leader);
            int slot = base + off;
            if (valid && slot < CAP_SIDE)
                pairs[(size_t)k * CAP_SIDE + slot] = make_int2(q, p);
        }

        // mirror entry -> list 25-k (winners only: one per occupied nbr cell)
        bool mv = valid && isW;
        unsigned long long m2 = __ballot(mv);
        if (m2) {
            int leader = __ffsll((long long)m2) - 1;
            int cnt    = __popcll(m2);
            int off    = __popcll(m2 & ((1ull << lane) - 1ull));
            int base = 0;
            if (lane == leader) base = atomicAdd(&cursors[(25 - k) * CURS_STRIDE], cnt);
            base = __shfl(base, leader);
            int slot = base + off;
            if (mv && slot < CAP_SIDE)
                pairs[(size_t)(25 - k) * CAP_SIDE + slot] = make_int2(w, q);
        }
    }
}

// ---------------------------------------------------------------------------
// K4: side-offset gather-GEMM-scatter. One block = one offset, 64 pairs.
// W staged in LDS once per block; half-wave per pair; atomicAdd scatter.
// ---------------------------------------------------------------------------
__global__ __launch_bounds__(256) void conv_side(
    const float* __restrict__ feat, const float* __restrict__ wt2,
    const int* __restrict__ cursors, const int2* __restrict__ pairs,
    float* __restrict__ out)
{
    int si = blockIdx.y;                    // 0..25
    int k  = (si < 13) ? si : si + 1;       // weight index (skip center 13)
    int cnt = cursors[si * CURS_STRIDE];
    if (cnt > CAP_SIDE) cnt = CAP_SIDE;
    int base = blockIdx.x * PAIRS_PER_BLOCK;
    if (base >= cnt) return;                // uniform early-exit (before barrier)

    __shared__ float4 wlds[16 * COUT];      // 24576 B
    {
        const float4* src = (const float4*)(wt2 + (size_t)k * 16 * COUT * 4);
        for (int i = threadIdx.x; i < 16 * COUT; i += 256) wlds[i] = src[i];
    }
    __syncthreads();

    int hw = threadIdx.x >> 5;
    int h  = threadIdx.x & 31;
    const int2* seg = pairs + (size_t)si * CAP_SIDE;

    for (int j = hw; j < PAIRS_PER_BLOCK; j += 8) {
        int idx = base + j;
        if (idx >= cnt) break;
        int2 pr = seg[idx];
        const float4* fp = (const float4*)(feat + (size_t)pr.x * CIN);

        float a0 = 0.f, a1 = 0.f, a2 = 0.f;
        #pragma unroll
        for (int ci4 = 0; ci4 < 16; ++ci4) {
            float4 f  = fp[ci4];
            const float4* w = &wlds[ci4 * COUT];
            float4 wa = w[h], wb = w[h + 32], wc = w[h + 64];
            a0 = fmaf(f.w, wa.w, fmaf(f.z, wa.z, fmaf(f.y, wa.y, fmaf(f.x, wa.x, a0))));
            a1 = fmaf(f.w, wb.w, fmaf(f.z, wb.z, fmaf(f.y, wb.y, fmaf(f.x, wb.x, a1))));
            a2 = fmaf(f.w, wc.w, fmaf(f.z, wc.z, fmaf(f.y, wc.y, fmaf(f.x, wc.x, a2))));
        }
        float* op = out + (size_t)pr.y * COUT;
        atomicAdd(op + h,      a0);
        atomicAdd(op + h + 32, a1);
        atomicAdd(op + h + 64, a2);
    }
}

// ---------------------------------------------------------------------------
// K5: center contribution + bias + LayerNorm + ReLU, in place on `out`.
// Winners only (w == p): losers handled by dup_fix. Coalesced feat reads.
// ---------------------------------------------------------------------------
__global__ __launch_bounds__(256) void center_ln_relu(
    const float* __restrict__ feat, const int* __restrict__ winner,
    const float* __restrict__ wt2,
    const float* __restrict__ bias, const float* __restrict__ gamma,
    const float* __restrict__ beta, float* __restrict__ out, int N)
{
    __shared__ float4 wlds[16 * COUT];
    {
        const float4* src = (const float4*)(wt2 + (size_t)13 * 16 * COUT * 4);
        for (int i = threadIdx.x; i < 16 * COUT; i += 256) wlds[i] = src[i];
    }
    __syncthreads();

    int hw = threadIdx.x >> 5;
    int h  = threadIdx.x & 31;
    float b0 = bias[h], b1 = bias[h + 32], b2 = bias[h + 64];
    float g0 = gamma[h], g1 = gamma[h + 32], g2 = gamma[h + 64];
    float e0 = beta[h],  e1 = beta[h + 32],  e2 = beta[h + 64];

    int pbase = blockIdx.x * 128;
    for (int i = 0; i < 16; ++i) {
        int p = pbase + i * 8 + hw;
        if (p >= N) continue;               // uniform within the half-wave
        int w = winner[p];
        if (w != p) continue;               // loser: dup_fix copies winner row

        const float4* fp = (const float4*)(feat + (size_t)p * CIN);
        float* op = out + (size_t)p * COUT;
        float a0 = op[h]      + b0;
        float a1 = op[h + 32] + b1;
        float a2 = op[h + 64] + b2;

        #pragma unroll
        for (int ci4 = 0; ci4 < 16; ++ci4) {
            float4 f  = fp[ci4];
            const float4* wv = &wlds[ci4 * COUT];
            float4 wa = wv[h], wb = wv[h + 32], wc = wv[h + 64];
            a0 = fmaf(f.w, wa.w, fmaf(f.z, wa.z, fmaf(f.y, wa.y, fmaf(f.x, wa.x, a0))));
            a1 = fmaf(f.w, wb.w, fmaf(f.z, wb.z, fmaf(f.y, wb.y, fmaf(f.x, wb.x, a1))));
            a2 = fmaf(f.w, wc.w, fmaf(f.z, wc.z, fmaf(f.y, wc.y, fmaf(f.x, wc.x, a2))));
        }

        float s  = a0 + a1 + a2;
        float s2 = a0 * a0 + a1 * a1 + a2 * a2;
        #pragma unroll
        for (int off = 16; off >= 1; off >>= 1) {
            s  += __shfl_xor(s, off);       // stays within the 32-lane half
            s2 += __shfl_xor(s2, off);
        }
        float mu  = s * (1.0f / COUT);
        float var = s2 * (1.0f / COUT) - mu * mu;
        float rs  = rsqrtf(var + 1e-5f);

        float o0 = (a0 - mu) * rs * g0 + e0;
        float o1 = (a1 - mu) * rs * g1 + e1;
        float o2 = (a2 - mu) * rs * g2 + e2;
        op[h]      = o0 > 0.f ? o0 : 0.f;
        op[h + 32] = o1 > 0.f ? o1 : 0.f;
        op[h + 64] = o2 > 0.f ? o2 : 0.f;
    }
}

// ---------------------------------------------------------------------------
// K6: duplicate-coordinate fixup — losers copy the winner's final row
// (identical coords => identical reference output). Runs after K5.
// ---------------------------------------------------------------------------
__global__ __launch_bounds__(256) void dup_fix(
    const int* __restrict__ winner, float* __restrict__ out, int N)
{
    int p = blockIdx.x * 8 + (threadIdx.x >> 5);
    if (p >= N) return;
    int w = winner[p];
    if (w == p) return;
    int h = threadIdx.x & 31;
    out[(size_t)p * COUT + h]      = out[(size_t)w * COUT + h];
    out[(size_t)p * COUT + h + 32] = out[(size_t)w * COUT + h + 32];
    out[(size_t)p * COUT + h + 64] = out[(size_t)w * COUT + h + 64];
}

// ---------------------------------------------------------------------------
extern "C" void kernel_launch(void* const* d_in, const int* in_sizes, int n_in,
                              void* d_out, int out_size, void* d_ws, size_t ws_size,
                              hipStream_t stream)
{
    const float* feat   = (const float*)d_in[0];
    const int*   coords = (const int*)d_in[1];
    const float* weight = (const float*)d_in[2];
    const float* bias   = (const float*)d_in[3];
    const float* gamma  = (const float*)d_in[4];
    const float* beta   = (const float*)d_in[5];
    float* out = (float*)d_out;

    int N = in_sizes[0] / CIN;   // 262144

    // Workspace layout (16B-aligned):
    //   voxel grid (int32) | repacked weight | padded cursors | winner | pairs
    char* wsp = (char*)d_ws;
    int*   grid_ws = (int*)wsp;                       wsp += (size_t)GRID_VOX * 4;
    float* wt2     = (float*)wsp;                     wsp += (size_t)NK * CIN * COUT * 4;
    int*   cursors = (int*)wsp;                       wsp += (size_t)NSIDE * CURS_STRIDE * 4;
    int*   winner  = (int*)wsp;                       wsp += (size_t)N * 4;
    int2*  pairs   = (int2*)wsp;

    hipMemsetAsync(grid_ws, 0xFF, (size_t)GRID_VOX * 4, stream);
    hipMemsetAsync(cursors, 0, (size_t)NSIDE * CURS_STRIDE * 4, stream);
    hipMemsetAsync(out, 0, (size_t)N * COUT * 4, stream);

    scatter_kernel<<<(N + 255) / 256, 256, 0, stream>>>(coords, grid_ws, N);
    repack_w<<<(NK * CIN * COUT + 255) / 256, 256, 0, stream>>>(weight, wt2);
    fill_pairs<<<(N + 255) / 256, 256, 0, stream>>>(coords, grid_ws, cursors,
                                                    pairs, winner, N);

    dim3 gside(CAP_SIDE / PAIRS_PER_BLOCK, 26);       // early-exit tail
    conv_side<<<gside, 256, 0, stream>>>(feat, wt2, cursors, pairs, out);

    center_ln_relu<<<(N + 127) / 128, 256, 0, stream>>>(
        feat, winner, wt2, bias, gamma, beta, out, N);

    dup_fix<<<(N + 7) / 8, 256, 0, stream>>>(winner, out, N);
}